// Round 8
// baseline (764.169 us; speedup 1.0000x reference)
//
#include <hip/hip_runtime.h>
#include <math.h>

#define NCLS 21
#define DD   256
#define HWPIX (512*512)          // 262144 pixels
#define HW2   (HWPIX/2)          // 131072 (f2 granularity)
#define EPSV  1e-6f

#define WT_STRIDE 24             // padded row stride (floats): 96 B, 16B-aligned rows
#define WT_FLOATS (DD*WT_STRIDE) // 6144 floats = 24 KB
#define THREADS 256
#define MAIN_BLOCKS (HW2/THREADS) // 512
#define UND 8                    // loads per prefetch group (two groups in flight)

typedef float __attribute__((ext_vector_type(2))) f2;
typedef float __attribute__((ext_vector_type(4))) f4;
typedef int   __attribute__((ext_vector_type(2))) i2;

// ---------------- kernel 0: per-class norm + transposed weight table ----------------
__global__ void prep_weights(const float* __restrict__ w,  // [NCLS][DD]
                             float* __restrict__ wt)       // [DD][WT_STRIDE]
{
    __shared__ float warr[4];
    __shared__ float inv_s;
    const int c = blockIdx.x, d = threadIdx.x;   // d in [0,256)
    float v = w[c*DD + d];
    float s = v * v;
    #pragma unroll
    for (int off = 32; off; off >>= 1) s += __shfl_xor(s, off, 64);
    int wave = d >> 6, lane = d & 63;
    if (lane == 0) warr[wave] = s;
    __syncthreads();
    if (d == 0) inv_s = 1.0f / fmaxf(sqrtf(warr[0]+warr[1]+warr[2]+warr[3]), EPSV);
    __syncthreads();
    wt[d*WT_STRIDE + c] = v * inv_s;
}

// ---------------- kernel 1: fused per-pixel pass + block reduction ----------------
// R7 lesson: weight reads MUST be off the vmcnt queue (they're VMEM if global,
// and vmcnt is ordered -> waiting on them drains all prefetches). LDS broadcast
// reads use lgkmcnt instead, so the vA/vB double-group keeps 8-16 fm loads in
// flight at ALL times: compute(A) waits vmcnt(8) while B is in flight.
__global__ __launch_bounds__(THREADS, 2)
void main_kernel(const float* __restrict__ yp,    // [NCLS][HWPIX]
                 const int*   __restrict__ ycrf,  // [HWPIX]
                 const int*   __restrict__ yret,  // [HWPIX]
                 const float* __restrict__ fm,    // [DD][HWPIX]
                 const float* __restrict__ wt,    // [DD][WT_STRIDE] (normalized, transposed)
                 float* __restrict__ partials)    // [MAIN_BLOCKS][4]
{
    __shared__ float lds_wt[WT_FLOATS];
    __shared__ float red[4][4];

    const int tid = threadIdx.x;

    // stage normalized weights into LDS (24 KB): broadcast source for all waves
    {
        const f4* src = (const f4*)wt;
        f4* dst = (f4*)lds_wt;
        #pragma unroll
        for (int i = 0; i < WT_FLOATS/4/THREADS; ++i)
            dst[i*THREADS + tid] = src[i*THREADS + tid];
    }
    __syncthreads();

    const int g = blockIdx.x * THREADS + tid;    // f2-pixel index
    const f2* fm2 = (const f2*)fm;
    const f2* yp2 = (const f2*)yp;
    const i2* yc2 = (const i2*)ycrf;
    const i2* yr2 = (const i2*)yret;

    float dot0[NCLS], dot1[NCLS];
    float nn0 = 0.f, nn1 = 0.f;
    #pragma unroll
    for (int c = 0; c < NCLS; ++c) { dot0[c] = 0.f; dot1[c] = 0.f; }

    // ---- dot products with normalized weights + feature norm ----
    f2 vA[UND], vB[UND];
    #pragma unroll
    for (int u = 0; u < UND; ++u)
        vA[u] = __builtin_nontemporal_load(&fm2[u*HW2 + g]);
    #pragma unroll
    for (int u = 0; u < UND; ++u)
        vB[u] = __builtin_nontemporal_load(&fm2[(UND + u)*HW2 + g]);

    // compute phase touches ONLY LDS (lgkmcnt) + registers: vmcnt stays >= 8
    #define COMPUTE(VREG, DBASE)                                              \
        do {                                                                  \
            _Pragma("unroll")                                                 \
            for (int u = 0; u < UND; ++u) {                                   \
                float wreg[24];                                               \
                const f4* wr4 = (const f4*)&lds_wt[((DBASE) + u)*WT_STRIDE];  \
                _Pragma("unroll")                                             \
                for (int i = 0; i < 6; ++i) ((f4*)wreg)[i] = wr4[i];          \
                float vx = VREG[u].x, vy = VREG[u].y;                         \
                _Pragma("unroll")                                             \
                for (int c = 0; c < NCLS; ++c) {                              \
                    dot0[c] = fmaf(vx, wreg[c], dot0[c]);                     \
                    dot1[c] = fmaf(vy, wreg[c], dot1[c]);                     \
                }                                                             \
                nn0 = fmaf(vx, vx, nn0);                                      \
                nn1 = fmaf(vy, vy, nn1);                                      \
            }                                                                 \
        } while (0)

    for (int d0 = 0; d0 < DD; d0 += 2*UND) {
        COMPUTE(vA, d0);                          // waits vA only; vB in flight
        if (d0 + 2*UND < DD) {
            #pragma unroll
            for (int u = 0; u < UND; ++u)
                vA[u] = __builtin_nontemporal_load(&fm2[(d0 + 2*UND + u)*HW2 + g]);
        }
        COMPUTE(vB, d0 + UND);                    // waits vB only; vA' in flight
        if (d0 + 3*UND < DD) {
            #pragma unroll
            for (int u = 0; u < UND; ++u)
                vB[u] = __builtin_nontemporal_load(&fm2[(d0 + 3*UND + u)*HW2 + g]);
        }
    }
    #undef COMPUTE

    const i2 yc = yc2[g], yr = yr2[g];

    // ---- corr / conf ----
    float inv_fn0 = 1.0f / fmaxf(sqrtf(nn0), EPSV);
    float inv_fn1 = 1.0f / fmaxf(sqrtf(nn1), EPSV);
    float cs0 = 0.f, cs1 = 0.f, cm0 = 0.f, cm1 = 0.f;  // cm init 0 == max(...,0)
    #pragma unroll
    for (int c = 0; c < NCLS; ++c) {
        float c0 = fmaf(dot0[c], inv_fn0, 1.0f);
        float c1 = fmaf(dot1[c], inv_fn1, 1.0f);
        cm0 = fmaxf(cm0, c0);
        cm1 = fmaxf(cm1, c1);
        cs0 = (yc.x == c) ? c0 : cs0;
        cs1 = (yc.y == c) ? c1 : cs1;
    }
    float r0 = cs0 / cm0, r1 = cs1 / cm1;
    float conf0 = r0 * r0, conf1 = r1 * r1;            // GAMMA = 2

    // ---- log-prob pass (21 independent NT loads, issued together) ----
    f2 p[NCLS];
    #pragma unroll
    for (int c = 0; c < NCLS; ++c)
        p[c] = __builtin_nontemporal_load(&yp2[c*HW2 + g]);

    float slp0 = 0.f, slp1 = 0.f, lpc0 = 0.f, lpc1 = 0.f;
    #pragma unroll
    for (int c = 0; c < NCLS; ++c) {
        float l0 = __logf(p[c].x), l1 = __logf(p[c].y);
        slp0 += l0; slp1 += l1;
        lpc0 = (yc.x == c) ? l0 : lpc0;
        lpc1 = (yc.y == c) ? l1 : lpc1;
    }

    const bool s0 = (yc.x == yr.x), s1 = (yc.y == yr.y);
    float sl0 = s0 ? lpc0 : 0.f,  sl1 = s1 ? lpc1 : 0.f;
    float a_nce = sl0 + sl1;
    float a_dce = (s0 ? 1.f : 0.f) + (s1 ? 1.f : 0.f);
    float a_dw  = conf0 * ((float)NCLS - (s0 ? 1.f : 0.f))
                + conf1 * ((float)NCLS - (s1 ? 1.f : 0.f));
    float a_nw  = conf0 * (slp0 - sl0) + conf1 * (slp1 - sl1);

    // ---- block reduction ----
    #pragma unroll
    for (int off = 32; off; off >>= 1) {
        a_nce += __shfl_xor(a_nce, off, 64);
        a_dce += __shfl_xor(a_dce, off, 64);
        a_dw  += __shfl_xor(a_dw,  off, 64);
        a_nw  += __shfl_xor(a_nw,  off, 64);
    }
    int wave = tid >> 6, lane = tid & 63;
    if (lane == 0) { red[wave][0]=a_nce; red[wave][1]=a_dce; red[wave][2]=a_dw; red[wave][3]=a_nw; }
    __syncthreads();
    if (tid == 0) {
        #pragma unroll
        for (int i = 0; i < 4; ++i)
            partials[blockIdx.x*4 + i] = red[0][i] + red[1][i] + red[2][i] + red[3][i];
    }
}

// ---------------- kernel 2: final reduction + loss assembly ----------------
__global__ void finalize(const float* __restrict__ partials, float* __restrict__ out)
{
    __shared__ float red[4][4];
    int tid = threadIdx.x;
    float s[4] = {0.f, 0.f, 0.f, 0.f};
    for (int b = tid; b < MAIN_BLOCKS; b += THREADS) {
        #pragma unroll
        for (int i = 0; i < 4; ++i) s[i] += partials[b*4 + i];
    }
    #pragma unroll
    for (int off = 32; off; off >>= 1) {
        #pragma unroll
        for (int i = 0; i < 4; ++i) s[i] += __shfl_xor(s[i], off, 64);
    }
    int wave = tid >> 6, lane = tid & 63;
    if (lane == 0) { red[wave][0]=s[0]; red[wave][1]=s[1]; red[wave][2]=s[2]; red[wave][3]=s[3]; }
    __syncthreads();
    if (tid == 0) {
        float nce = red[0][0]+red[1][0]+red[2][0]+red[3][0];
        float dce = red[0][1]+red[1][1]+red[2][1]+red[3][1];
        float dw  = red[0][2]+red[1][2]+red[2][2]+red[3][2];
        float nw  = red[0][3]+red[1][3]+red[2][3]+red[3][3];
        float ce  = -nce / dce;
        float wce = -nw  / dw;
        out[0] = ce + 0.1f * wce;
        out[1] = ce;
        out[2] = wce;
    }
}

extern "C" void kernel_launch(void* const* d_in, const int* in_sizes, int n_in,
                              void* d_out, int out_size, void* d_ws, size_t ws_size,
                              hipStream_t stream) {
    const float* y_pred = (const float*)d_in[0];
    const int*   ycrf   = (const int*)d_in[1];
    const int*   yret   = (const int*)d_in[2];
    const float* fmap   = (const float*)d_in[3];
    const float* cw     = (const float*)d_in[4];
    float* out = (float*)d_out;

    float* wt       = (float*)d_ws;                 // 24 KB
    float* partials = wt + WT_FLOATS;               // 512*4 floats = 8 KB

    prep_weights<<<NCLS, THREADS, 0, stream>>>(cw, wt);
    main_kernel<<<MAIN_BLOCKS, THREADS, 0, stream>>>(y_pred, ycrf, yret, fmap, wt, partials);
    finalize<<<1, THREADS, 0, stream>>>(partials, out);
}

// Round 11
// 73.457 us; speedup vs baseline: 10.4030x; 10.4030x over previous
//
#include <hip/hip_runtime.h>
#include <math.h>

#define NCLS 21
#define DD   256
#define HWPIX (512*512)            // 262144 pixels
#define PIX  4                     // pixels per lane (f4)
#define HW4  (HWPIX/PIX)           // 65536 f4-groups
#define EPSV 1e-6f

#define WT_STRIDE 24               // padded row stride (floats): 96 B, 16B-aligned rows
#define WT_FLOATS (DD*WT_STRIDE)   // 6144 floats = 24 KB
#define THREADS 256
#define MAIN_BLOCKS (HW4/THREADS)  // 256 -> exactly 1 block per CU
#define UND 8                      // fm prefetch depth (8 x 16B in flight per lane)

typedef float __attribute__((ext_vector_type(2))) f2;
typedef float __attribute__((ext_vector_type(4))) f4;
typedef int   __attribute__((ext_vector_type(4))) i4;

// ---------------- kernel 0: per-class norm + transposed weight table ----------------
__global__ void prep_weights(const float* __restrict__ w,  // [NCLS][DD]
                             float* __restrict__ wt)       // [DD][WT_STRIDE]
{
    __shared__ float warr[4];
    __shared__ float inv_s;
    const int c = blockIdx.x, d = threadIdx.x;   // d in [0,256)
    float v = w[c*DD + d];
    float s = v * v;
    #pragma unroll
    for (int off = 32; off; off >>= 1) s += __shfl_xor(s, off, 64);
    int wave = d >> 6, lane = d & 63;
    if (lane == 0) warr[wave] = s;
    __syncthreads();
    if (d == 0) inv_s = 1.0f / fmaxf(sqrtf(warr[0]+warr[1]+warr[2]+warr[3]), EPSV);
    __syncthreads();
    wt[d*WT_STRIDE + c] = v * inv_s;
}

// ---------------- kernel 1: fused per-pixel pass + block reduction ----------------
// Broadcast-amortization: PIX=4 pixels/lane halves the per-CU LDS broadcast
// cost vs f2 (the measured ~65us pin of R3/R4). wregA/wregB register double
// buffer: row d's 42 pk-FMAs cover row d+1's 6 ds_read_b128. No launch_bounds
// min-waves: grid = 1 block/CU fixes occupancy, VGPR cap 512 -> no spill (R8).
__global__ __launch_bounds__(THREADS)
void main_kernel(const float* __restrict__ yp,    // [NCLS][HWPIX]
                 const int*   __restrict__ ycrf,  // [HWPIX]
                 const int*   __restrict__ yret,  // [HWPIX]
                 const float* __restrict__ fm,    // [DD][HWPIX]
                 const float* __restrict__ wt,    // [DD][WT_STRIDE] (normalized, transposed)
                 float* __restrict__ partials)    // [MAIN_BLOCKS][4]
{
    __shared__ float lds_wt[WT_FLOATS];
    __shared__ float red[4][4];

    const int tid = threadIdx.x;

    // stage normalized weights into LDS (24 KB)
    {
        const f4* src = (const f4*)wt;
        f4* dst = (f4*)lds_wt;
        #pragma unroll
        for (int i = 0; i < WT_FLOATS/4/THREADS; ++i)
            dst[i*THREADS + tid] = src[i*THREADS + tid];
    }
    __syncthreads();

    const int g = blockIdx.x * THREADS + tid;    // f4-pixel index
    const f4* fm4 = (const f4*)fm;
    const f4* yp4 = (const f4*)yp;
    const i4* yc4 = (const i4*)ycrf;
    const i4* yr4 = (const i4*)yret;

    f2 dotA[NCLS], dotB[NCLS];                   // px{0,1}, px{2,3}
    f2 nnA = {0.f, 0.f}, nnB = {0.f, 0.f};
    #pragma unroll
    for (int c = 0; c < NCLS; ++c) { dotA[c] = nnA; dotB[c] = nnA; }

    float wrA[24], wrB[24];
    {   // row 0 into wrA
        const f4* wr4 = (const f4*)&lds_wt[0];
        #pragma unroll
        for (int i = 0; i < 6; ++i) ((f4*)wrA)[i] = wr4[i];
    }

    f4 v[UND];
    #pragma unroll
    for (int u = 0; u < UND; ++u)
        v[u] = __builtin_nontemporal_load(&fm4[u*HW4 + g]);

    // one d-row: issue next row's ds_reads into WN, compute with WC
    #define ROW(VV, WC, WN, DN)                                           \
        do {                                                              \
            const int _dn = (DN) & (DD - 1);                              \
            const f4* _wr4 = (const f4*)&lds_wt[_dn*WT_STRIDE];           \
            _Pragma("unroll")                                             \
            for (int i = 0; i < 6; ++i) ((f4*)(WN))[i] = _wr4[i];         \
            f2 _va = {(VV).x, (VV).y}, _vb = {(VV).z, (VV).w};            \
            _Pragma("unroll")                                             \
            for (int c = 0; c < NCLS; ++c) {                              \
                dotA[c] += _va * (WC)[c];                                 \
                dotB[c] += _vb * (WC)[c];                                 \
            }                                                             \
            nnA += _va * _va;                                             \
            nnB += _vb * _vb;                                             \
        } while (0)

    for (int d0 = 0; d0 < DD; d0 += UND) {
        f4 nv[UND];
        if (d0 + UND < DD) {
            #pragma unroll
            for (int u = 0; u < UND; ++u)
                nv[u] = __builtin_nontemporal_load(&fm4[(d0 + UND + u)*HW4 + g]);
        }
        ROW(v[0], wrA, wrB, d0 + 1);
        ROW(v[1], wrB, wrA, d0 + 2);
        ROW(v[2], wrA, wrB, d0 + 3);
        ROW(v[3], wrB, wrA, d0 + 4);
        ROW(v[4], wrA, wrB, d0 + 5);
        ROW(v[5], wrB, wrA, d0 + 6);
        ROW(v[6], wrA, wrB, d0 + 7);
        ROW(v[7], wrB, wrA, d0 + 8);
        #pragma unroll
        for (int u = 0; u < UND; ++u) v[u] = nv[u];
    }
    #undef ROW

    const i4 yc = yc4[g], yr = yr4[g];

    // ---- corr / conf, per pixel k=0..3 ----
    float conf[PIX];
    {
        float nn[PIX] = { nnA.x, nnA.y, nnB.x, nnB.y };
        int   yck[PIX] = { yc.x, yc.y, yc.z, yc.w };
        #pragma unroll
        for (int k = 0; k < PIX; ++k) {
            float inv_fn = 1.0f / fmaxf(sqrtf(nn[k]), EPSV);
            float cs = 0.f, cm = 0.f;            // cm init 0 == max(...,0)
            #pragma unroll
            for (int c = 0; c < NCLS; ++c) {
                float d = (k == 0) ? dotA[c].x : (k == 1) ? dotA[c].y
                        : (k == 2) ? dotB[c].x : dotB[c].y;
                float cv = fmaf(d, inv_fn, 1.0f);
                cm = fmaxf(cm, cv);
                cs = (yck[k] == c) ? cv : cs;
            }
            float r = cs / cm;
            conf[k] = r * r;                     // GAMMA = 2
        }
    }

    // ---- log-prob pass (21 independent NT f4 loads) ----
    f4 p[NCLS];
    #pragma unroll
    for (int c = 0; c < NCLS; ++c)
        p[c] = __builtin_nontemporal_load(&yp4[c*HW4 + g]);

    float slp[PIX] = {0.f,0.f,0.f,0.f}, lpc[PIX] = {0.f,0.f,0.f,0.f};
    {
        int yck[PIX] = { yc.x, yc.y, yc.z, yc.w };
        #pragma unroll
        for (int c = 0; c < NCLS; ++c) {
            float l0 = __logf(p[c].x), l1 = __logf(p[c].y);
            float l2 = __logf(p[c].z), l3 = __logf(p[c].w);
            slp[0] += l0; slp[1] += l1; slp[2] += l2; slp[3] += l3;
            lpc[0] = (yck[0] == c) ? l0 : lpc[0];
            lpc[1] = (yck[1] == c) ? l1 : lpc[1];
            lpc[2] = (yck[2] == c) ? l2 : lpc[2];
            lpc[3] = (yck[3] == c) ? l3 : lpc[3];
        }
    }

    float a_nce = 0.f, a_dce = 0.f, a_dw = 0.f, a_nw = 0.f;
    {
        int yck[PIX] = { yc.x, yc.y, yc.z, yc.w };
        int yrk[PIX] = { yr.x, yr.y, yr.z, yr.w };
        #pragma unroll
        for (int k = 0; k < PIX; ++k) {
            bool s = (yck[k] == yrk[k]);
            float sf = s ? 1.f : 0.f;
            float sl = s ? lpc[k] : 0.f;
            a_nce += sl;
            a_dce += sf;
            a_dw  += conf[k] * ((float)NCLS - sf);
            a_nw  += conf[k] * (slp[k] - sl);
        }
    }

    // ---- block reduction ----
    #pragma unroll
    for (int off = 32; off; off >>= 1) {
        a_nce += __shfl_xor(a_nce, off, 64);
        a_dce += __shfl_xor(a_dce, off, 64);
        a_dw  += __shfl_xor(a_dw,  off, 64);
        a_nw  += __shfl_xor(a_nw,  off, 64);
    }
    int wave = tid >> 6, lane = tid & 63;
    if (lane == 0) { red[wave][0]=a_nce; red[wave][1]=a_dce; red[wave][2]=a_dw; red[wave][3]=a_nw; }
    __syncthreads();
    if (tid == 0) {
        #pragma unroll
        for (int i = 0; i < 4; ++i)
            partials[blockIdx.x*4 + i] = red[0][i] + red[1][i] + red[2][i] + red[3][i];
    }
}

// ---------------- kernel 2: final reduction + loss assembly ----------------
__global__ void finalize(const float* __restrict__ partials, float* __restrict__ out)
{
    __shared__ float red[4][4];
    int tid = threadIdx.x;
    float s[4] = {0.f, 0.f, 0.f, 0.f};
    for (int b = tid; b < MAIN_BLOCKS; b += THREADS) {
        #pragma unroll
        for (int i = 0; i < 4; ++i) s[i] += partials[b*4 + i];
    }
    #pragma unroll
    for (int off = 32; off; off >>= 1) {
        #pragma unroll
        for (int i = 0; i < 4; ++i) s[i] += __shfl_xor(s[i], off, 64);
    }
    int wave = tid >> 6, lane = tid & 63;
    if (lane == 0) { red[wave][0]=s[0]; red[wave][1]=s[1]; red[wave][2]=s[2]; red[wave][3]=s[3]; }
    __syncthreads();
    if (tid == 0) {
        float nce = red[0][0]+red[1][0]+red[2][0]+red[3][0];
        float dce = red[0][1]+red[1][1]+red[2][1]+red[3][1];
        float dw  = red[0][2]+red[1][2]+red[2][2]+red[3][2];
        float nw  = red[0][3]+red[1][3]+red[2][3]+red[3][3];
        float ce  = -nce / dce;
        float wce = -nw  / dw;
        out[0] = ce + 0.1f * wce;
        out[1] = ce;
        out[2] = wce;
    }
}

extern "C" void kernel_launch(void* const* d_in, const int* in_sizes, int n_in,
                              void* d_out, int out_size, void* d_ws, size_t ws_size,
                              hipStream_t stream) {
    const float* y_pred = (const float*)d_in[0];
    const int*   ycrf   = (const int*)d_in[1];
    const int*   yret   = (const int*)d_in[2];
    const float* fmap   = (const float*)d_in[3];
    const float* cw     = (const float*)d_in[4];
    float* out = (float*)d_out;

    float* wt       = (float*)d_ws;                 // 24 KB
    float* partials = wt + WT_FLOATS;               // 256*4 floats = 4 KB

    prep_weights<<<NCLS, THREADS, 0, stream>>>(cw, wt);
    main_kernel<<<MAIN_BLOCKS, THREADS, 0, stream>>>(y_pred, ycrf, yret, fmap, wt, partials);
    finalize<<<1, THREADS, 0, stream>>>(partials, out);
}